// Round 3
// 1414.686 us; speedup vs baseline: 1.1562x; 1.1562x over previous
//
#include <hip/hip_runtime.h>

#define N_NODES 262144
#define MEM_DIM 512
#define MSG_DIM 1024
#define N_UPD   65536

typedef __attribute__((ext_vector_type(8)))  __bf16 bf16x8;
typedef __attribute__((ext_vector_type(16))) float  floatx16;
typedef __attribute__((ext_vector_type(4)))  float  floatx4;
typedef __attribute__((ext_vector_type(4)))  unsigned short ushortx4;

// inverse map node -> update index (or -1). Static device global: stays out of
// the workspace (ws footprint remains byte-identical to the proven layout).
__device__ __align__(16) int g_inv[N_NODES];

static __device__ __forceinline__ unsigned short f2bf(float f) {
  unsigned int u = __float_as_uint(f);
  u += 0x7fffu + ((u >> 16) & 1u);      // round-to-nearest-even
  return (unsigned short)(u >> 16);
}

static __device__ __forceinline__ ushortx4 cvt4(float4 v) {
  ushortx4 o;
  o.x = f2bf(v.x); o.y = f2bf(v.y); o.z = f2bf(v.z); o.w = f2bf(v.w);
  return o;
}

static __device__ __forceinline__ void async16(const void* g, void* l) {
  __builtin_amdgcn_global_load_lds(
      (const __attribute__((address_space(1))) unsigned int*)g,
      (__attribute__((address_space(3))) unsigned int*)l, 16, 0, 0);
}

// ---- k1: init inv map to -1, convert weights to bf16 ----
__global__ void prep_kernel(const float4* __restrict__ wih_f, ushortx4* __restrict__ wihb,
                            const float4* __restrict__ whh_f, ushortx4* __restrict__ whhb) {
  const int NI4 = N_NODES / 4;                 // 65536
  const int NW1 = 3 * MEM_DIM * MSG_DIM / 4;   // 393216
  const int NW2 = 3 * MEM_DIM * MEM_DIM / 4;   // 196608
  int4* inv4 = (int4*)g_inv;
  int stride = gridDim.x * blockDim.x;
  for (int i = blockIdx.x * blockDim.x + threadIdx.x; i < NI4 + NW1 + NW2; i += stride) {
    if (i < NI4) inv4[i] = make_int4(-1, -1, -1, -1);
    else if (i < NI4 + NW1) { int j = i - NI4; wihb[j] = cvt4(wih_f[j]); }
    else { int j = i - NI4 - NW1; whhb[j] = cvt4(whh_f[j]); }
  }
}

// ---- k2: scatter inverse map + timestamps (ids are unique) ----
__global__ void scatter_kernel(const int* __restrict__ ids,
                               const float* __restrict__ ts, float* __restrict__ out_lu) {
  int u = blockIdx.x * blockDim.x + threadIdx.x;   // grid exactly N_UPD
  int g = ids[u];
  g_inv[g] = u;
  out_lu[g] = ts[u];
}

// ---- k3: single pass over memory (copy non-updated rows OR emit bf16 h for
//          updated rows), convert messages, copy non-updated last_update ----
__global__ void mega_kernel(const float4* __restrict__ mem, const float* __restrict__ lu,
                            const float4* __restrict__ msg,
                            float4* __restrict__ out_mem, float* __restrict__ out_lu,
                            ushortx4* __restrict__ hb4, ushortx4* __restrict__ msgb4) {
  const int NM4 = N_NODES * MEM_DIM / 4;   // 33554432
  const int NG4 = N_UPD * MSG_DIM / 4;     // 16777216
  int stride = gridDim.x * blockDim.x;     // multiple of 128 => row uniform per wave
  for (int i = blockIdx.x * blockDim.x + threadIdx.x; i < NM4 + NG4 + N_NODES; i += stride) {
    if (i < NM4) {
      int row = i >> 7;
      int iv = g_inv[row];                 // broadcast across the wave (cache hit)
      float4 v = mem[i];
      if (iv < 0)
        __builtin_nontemporal_store(*(const floatx4*)&v, (floatx4*)&out_mem[i]);
      else
        hb4[((size_t)iv << 7) + (i & 127)] = cvt4(v);
    } else if (i < NM4 + NG4) {
      int j = i - NM4;
      msgb4[j] = cvt4(msg[j]);
    } else {
      int j = i - NM4 - NG4;
      if (g_inv[j] < 0) out_lu[j] = lu[j]; // updated entries already written by k2
    }
  }
}

// ---- fused dual-GEMM + GRU + scatter ----
// block: 256 thr (4 waves). tile: BM=128 rows x BH=64 h-cols.
// T2 swizzle: global_load_lds dest stays linear; the per-lane GLOBAL source
// column is pre-swizzled (slot ^= row&7) and fragment reads XOR the same
// pattern back (involution). Kills the 128B-row-stride bank conflict.
// T1: chunked XCD swizzle so the 8 hc-blocks sharing an A-slab land on one XCD.
__global__ __launch_bounds__(256, 2)
void gru_kernel(const unsigned short* __restrict__ msgb,
                const unsigned short* __restrict__ hb,
                const unsigned short* __restrict__ wih,
                const unsigned short* __restrict__ whh,
                const float* __restrict__ b_ih, const float* __restrict__ b_hh,
                const float* __restrict__ memory,
                const int* __restrict__ ids,
                float* __restrict__ out_mem) {
  __shared__ unsigned short sA[128 * 64];   // 16 KB, linear (global_load_lds dest)
  __shared__ unsigned short sB[192 * 64];   // 24 KB (3 gate row-groups x 64)

  const int tid  = threadIdx.x;
  const int lane = tid & 63;
  const int w    = tid >> 6;
  const int wm   = w & 1, wn = w >> 1;

  // chunked XCD swizzle: bid%8==XCD; give each XCD contiguous m-tiles with all
  // 8 hc-blocks of an m-tile temporally adjacent (A-slab L2 reuse). 4096%8==0.
  const int bid = blockIdx.x;
  const int swz = (bid & 7) * 512 + (bid >> 3);
  const int hc  = (swz & 7) * 64;
  const int m0  = (swz >> 3) * 128;

  floatx16 accR[2], accZ[2], accN[2][2];
#pragma unroll
  for (int t = 0; t < 2; ++t)
#pragma unroll
    for (int e = 0; e < 16; ++e) {
      accR[t][e] = 0.f; accZ[t][e] = 0.f;
      accN[0][t][e] = 0.f; accN[1][t][e] = 0.f;
    }

  const int srow = tid >> 3;                          // staging row in 32-row round
  const int scol = (((tid & 7) ^ (srow & 7)) << 3);   // pre-swizzled global k-col (bf16)
  const int lrow = lane & 31;
  const int lko  = (lane >> 5) * 8;                   // frag k offset
  const int ksw  = (lrow & 7) << 3;                   // read-side XOR (bf16 units)

#pragma unroll
  for (int phase = 0; phase < 2; ++phase) {
    const unsigned short* Ap = phase ? hb : msgb;
    const unsigned short* Bp = phase ? whh : wih;
    const int K = phase ? 512 : 1024;
    for (int k0 = 0; k0 < K; k0 += 64) {
      __syncthreads();
      // stage A: 128x64 bf16, 4 rounds of 32 rows (LDS dest linear)
#pragma unroll
      for (int j = 0; j < 4; ++j) {
        const unsigned short* g = Ap + (size_t)(m0 + j * 32 + srow) * K + (k0 + scol);
        async16(g, (char*)sA + j * 4096 + w * 1024);
      }
      // stage B: 192x64 bf16 (gates r,z,n), 6 rounds
#pragma unroll
      for (int j = 0; j < 6; ++j) {
        int brr  = j * 32 + srow;            // 0..191
        int gate = brr >> 6;                 // 0..2
        int wr   = gate * 512 + hc + (brr & 63);
        const unsigned short* g = Bp + (size_t)wr * K + (k0 + scol);
        async16(g, (char*)sB + j * 4096 + w * 1024);
      }
      __syncthreads();
#pragma unroll
      for (int kk = 0; kk < 4; ++kk) {
        int kos = (kk * 16 + lko) ^ ksw;     // swizzled read column
        bf16x8 a0 = *(const bf16x8*)&sA[(wm * 64 + lrow) * 64 + kos];
        bf16x8 a1 = *(const bf16x8*)&sA[(wm * 64 + 32 + lrow) * 64 + kos];
        bf16x8 vr = *(const bf16x8*)&sB[(wn * 32 + lrow) * 64 + kos];
        bf16x8 vz = *(const bf16x8*)&sB[(64 + wn * 32 + lrow) * 64 + kos];
        bf16x8 vn = *(const bf16x8*)&sB[(128 + wn * 32 + lrow) * 64 + kos];
        accR[0] = __builtin_amdgcn_mfma_f32_32x32x16_bf16(a0, vr, accR[0], 0, 0, 0);
        accR[1] = __builtin_amdgcn_mfma_f32_32x32x16_bf16(a1, vr, accR[1], 0, 0, 0);
        accZ[0] = __builtin_amdgcn_mfma_f32_32x32x16_bf16(a0, vz, accZ[0], 0, 0, 0);
        accZ[1] = __builtin_amdgcn_mfma_f32_32x32x16_bf16(a1, vz, accZ[1], 0, 0, 0);
        accN[phase][0] = __builtin_amdgcn_mfma_f32_32x32x16_bf16(a0, vn, accN[phase][0], 0, 0, 0);
        accN[phase][1] = __builtin_amdgcn_mfma_f32_32x32x16_bf16(a1, vn, accN[phase][1], 0, 0, 0);
      }
    }
  }

  // epilogue: GRU gates + scatter to out_mem[ids[m]]
  const int col = hc + wn * 32 + lrow;
  const float biasR  = b_ih[col] + b_hh[col];
  const float biasZ  = b_ih[512 + col] + b_hh[512 + col];
  const float biasNi = b_ih[1024 + col];
  const float biasNh = b_hh[1024 + col];
#pragma unroll
  for (int t = 0; t < 2; ++t) {
#pragma unroll
    for (int r = 0; r < 16; ++r) {
      int rowin = (r & 3) + 8 * (r >> 2) + 4 * (lane >> 5);
      int m = m0 + wm * 64 + t * 32 + rowin;
      int g = ids[m];
      size_t off = (size_t)g * MEM_DIM + col;
      float h  = memory[off];
      float rr = __builtin_amdgcn_rcpf(1.f + __expf(-(accR[t][r] + biasR)));
      float zz = __builtin_amdgcn_rcpf(1.f + __expf(-(accZ[t][r] + biasZ)));
      float ni = accN[0][t][r] + biasNi;
      float hn = accN[1][t][r] + biasNh;
      float e  = __expf(2.f * (ni + rr * hn));
      float nn = 1.f - 2.f * __builtin_amdgcn_rcpf(e + 1.f);
      __builtin_nontemporal_store((1.f - zz) * nn + zz * h, &out_mem[off]);
    }
  }
}

extern "C" void kernel_launch(void* const* d_in, const int* in_sizes, int n_in,
                              void* d_out, int out_size, void* d_ws, size_t ws_size,
                              hipStream_t stream) {
  const float* memory      = (const float*)d_in[0];
  const float* last_update = (const float*)d_in[1];
  const int*   node_ids    = (const int*)d_in[2];
  const float* messages    = (const float*)d_in[3];
  const float* timestamps  = (const float*)d_in[4];
  const float* W_ih        = (const float*)d_in[5];
  const float* W_hh        = (const float*)d_in[6];
  const float* b_ih        = (const float*)d_in[7];
  const float* b_hh        = (const float*)d_in[8];

  float* out_mem = (float*)d_out;
  float* out_lu  = out_mem + (size_t)N_NODES * MEM_DIM;

  // workspace layout (bytes) — byte-identical to the proven footprint:
  //   wihb @0         (3 MB)
  //   whhb @3145728   (1.5 MB)
  //   msgb @4718592   (128 MB)
  //   hb   @138936320 (64 MB)  => ends at 206045184
  char* ws = (char*)d_ws;
  unsigned short* wihb = (unsigned short*)ws;
  unsigned short* whhb = (unsigned short*)(ws + 3145728);
  unsigned short* msgb = (unsigned short*)(ws + 4718592);
  unsigned short* hb   = (unsigned short*)(ws + 138936320);

  prep_kernel<<<1024, 256, 0, stream>>>((const float4*)W_ih, (ushortx4*)wihb,
                                        (const float4*)W_hh, (ushortx4*)whhb);
  scatter_kernel<<<N_UPD / 256, 256, 0, stream>>>(node_ids, timestamps, out_lu);
  mega_kernel<<<4096, 256, 0, stream>>>((const float4*)memory, last_update,
                                        (const float4*)messages,
                                        (float4*)out_mem, out_lu,
                                        (ushortx4*)hb, (ushortx4*)msgb);
  gru_kernel<<<4096, 256, 0, stream>>>(msgb, hb, wihb, whhb, b_ih, b_hh,
                                       memory, node_ids, out_mem);
}